// Round 11
// baseline (239.581 us; speedup 1.0000x reference)
//
#include <hip/hip_runtime.h>
#include <hip/hip_fp16.h>

// L=8 layers, H=512, K=16 links, N_IN=512, B=8192; out = last 512 cols (fp32).
#define LAYERS 8
#define H      512
#define K      16
#define N_IN   512
#define BATCH  8192
#define R      8      // batch rows per block; 8 x f16 = 16 B -> one ds_read_b128 per gather
#define NT     512    // 8 waves/block; 64 KB LDS -> 2 blocks/CU -> 16 waves/CU
#define LDS_COLS 4096
#define PARAM_N  (LAYERS * H * K)   // 65536 params
#define SLOTS  8    // 16-B request slots per 128-B bank row

// History (fused dispatch / e2e):
//  R0 baseline: 50-54us / 109.9. VGPR 64 clean. Best e2e 108.9 (R8 round).
//  R5: static per-thread sort+rotate: conflicts only -12%; fused 48.2-49.6
//    (best seen); prep tax ~9us e2e.
//  R8/R9/R10: deeper same-chain read queues all regressed (55-67us).
//  R11: R=4 2x-occupancy: 74us. TLP theory dead.
//  R12: A/B split 2x ds_read_b64: conflicts 2x, +14us. LAW: counted
//    conflict/instr (~8.2) is size-independent; fewest widest reads win;
//    conflict cycles convert to time 1:1. Conflict block = 14.1us of ~50.
//  R13: joint wave-level schedule -- prep took 65us (LDS atomics + 320
//    syncthreads), buried the fused counters. Theory still untested.
//  R14 (this): same experiment, prep rewritten ballot-based in-register
//    (no LDS/atomics/barriers, ~3-5us): per step, lanes propose min-load
//    slot (rotating tie-break), per-slot ballot+prefix-popcount accepts up
//    to cap (relaxing 8->inf). Wave-uniform cnt in registers. Any outcome =
//    valid permutation -> exact result regardless. Fused = R3 PRESCALED.
//    Discriminator: conflicts <=4M -> imbalance model, fused ~41us;
//    conflicts >=7M -> divergence model, declare R0 roofline next round.

// ---- prep: per-(wavepos,layer) ballot-greedy edge coloring, 1 wave each ----
__global__ __launch_bounds__(64)
void ffn_sched_kernel(const int*   __restrict__ link_idx,
                      const float* __restrict__ weights,
                      int*         __restrict__ idx2,
                      float*       __restrict__ w2)
{
    const int lane    = threadIdx.x;          // 0..63
    const int wavepos = blockIdx.x & 7;       // wave within fused block
    const int layer   = blockIdx.x >> 3;      // 0..7
    const int base    = (layer * H + wavepos * 64 + lane) * K;

    int idx[K]; float w[K]; int slot[K];
    #pragma unroll
    for (int k = 0; k < K; ++k) {
        idx[k]  = link_idx[base + k];
        w[k]    = weights[base + k];
        slot[k] = idx[k] & (SLOTS - 1);
    }

    unsigned rem = 0xFFFFu;                   // entries not yet scheduled
    for (int j = 0; j < K; ++j) {             // time-step j
        int cnt[SLOTS];                        // wave-uniform (all lanes compute
        #pragma unroll                         // identical values from ballots)
        for (int s = 0; s < SLOTS; ++s) cnt[s] = 0;

        int chosen = -1;
        for (int round = 0; round < 12; ++round) {
            if (__ballot(chosen < 0) == 0ull) break;
            const int cap = (round < 10) ? (8 + round) : 10000;

            // propose: min-load slot among my remaining entries; rotating
            // scan start decorrelates ties across lanes/steps (anti-herding)
            int cent = -1, cslot = -1;
            if (chosen < 0) {
                int bestLoad = 1 << 30;
                #pragma unroll
                for (int t = 0; t < K; ++t) {
                    const int e = (t + lane + 3 * j) & 15;
                    if (rem & (1u << e)) {
                        const int ld = cnt[slot[e]];
                        if (ld < bestLoad) { bestLoad = ld; cent = e; cslot = slot[e]; }
                    }
                }
            }

            // per-slot acceptance: first (cap - cnt[s]) proposers win
            #pragma unroll
            for (int s = 0; s < SLOTS; ++s) {
                const unsigned long long m = __ballot(chosen < 0 && cslot == s);
                if (m) {
                    const int room = cap - cnt[s];
                    if (room > 0) {
                        if (chosen < 0 && cslot == s) {
                            const int before =
                                __popcll(m & ((1ull << lane) - 1ull));
                            if (before < room) { chosen = cent; rem &= ~(1u << cent); }
                        }
                        const int nprop = __popcll(m);
                        cnt[s] += (nprop < room) ? nprop : room;
                    }
                }
            }
        }
        // hard fallback (unreachable: cap=10000 accepts all by round 10)
        if (chosen < 0) {
            #pragma unroll
            for (int e = 0; e < K; ++e)
                if (chosen < 0 && (rem & (1u << e))) chosen = e;
            rem &= ~(1u << chosen);
        }
        idx2[base + j] = idx[chosen] << 4;    // pre-scaled byte offset
        w2 [base + j] = w[chosen];
    }
}

// PRESCALED=1: idxp holds byte offsets (scheduled path).
// PRESCALED=0: idxp is raw link_idx (fallback, shift in-kernel == R0).
template <int PRESCALED>
__global__ __launch_bounds__(NT, 2)
void ffn_fused_kernel(const float* __restrict__ x,
                      const int*   __restrict__ idxp,
                      const float* __restrict__ wp,
                      const float* __restrict__ bias,
                      float*       __restrict__ out)
{
    // vals[c*R + r] = f16 value of column c, block batch-row r.
    __shared__ __align__(16) __half vals[LDS_COLS * R];   // 65536 B

    const int tid  = threadIdx.x;
    const int row0 = blockIdx.x * R;

    // ---- Stage x rows into LDS as f16 (each thread owns one column) ----
    {
        const int c = tid;                     // NT == N_IN == 512
        float v[R];
        #pragma unroll
        for (int r = 0; r < R; ++r)
            v[r] = x[(row0 + r) * N_IN + c];   // coalesced per r
        __half2 p[R / 2];
        #pragma unroll
        for (int r = 0; r < R / 2; ++r)
            p[r] = __floats2half2_rn(v[2 * r], v[2 * r + 1]);
        *(uint4*)&vals[c * R] = *(const uint4*)p;   // one ds_write_b128
    }

    // ---- Preload layer-0 params while LDS staging drains (before barrier) ----
    int   idxA[K]; float wA[K]; float bA;
    {
        const int base = tid * K;              // l=0, h=tid
        #pragma unroll
        for (int q = 0; q < 4; ++q) {
            *(int4*)  &idxA[4 * q] = ((const int4*)  (idxp + base))[q];
            *(float4*)&wA  [4 * q] = ((const float4*)(wp   + base))[q];
        }
        if (!PRESCALED) {
            #pragma unroll
            for (int k = 0; k < K; ++k) idxA[k] <<= 4;
        }
        bA = bias[tid];
    }

    __syncthreads();

    // ---- Layers (each thread owns one h; 8 batch rows in registers) ----
    #pragma unroll
    for (int l = 0; l < LAYERS; ++l) {
        // Prefetch next layer's params under this layer's gather/FMA work.
        int idxB[K]; float wB[K]; float bB = 0.0f;
        if (l < LAYERS - 1) {
            const int nb = ((l + 1) * H + tid) * K;
            #pragma unroll
            for (int q = 0; q < 4; ++q) {
                *(int4*)  &idxB[4 * q] = ((const int4*)  (idxp + nb))[q];
                *(float4*)&wB  [4 * q] = ((const float4*)(wp   + nb))[q];
            }
            if (!PRESCALED) {
                #pragma unroll
                for (int k = 0; k < K; ++k) idxB[k] <<= 4;
            }
            bB = bias[(l + 1) * H + tid];
        }

        float acc[R];
        #pragma unroll
        for (int r = 0; r < R; ++r) acc[r] = bA;

        #pragma unroll
        for (int k = 0; k < K; ++k) {
            // one ds_read_b128 = 8 rows of the gathered column (byte offset)
            const uint4 g = *(const uint4*)((const char*)vals + idxA[k]);
            const __half2* hp = (const __half2*)&g;
            const float wk = wA[k];
            #pragma unroll
            for (int r = 0; r < R / 2; ++r) {
                const float2 f = __half22float2(hp[r]);   // folds into v_fma_mix_f32
                acc[2 * r]     = fmaf(f.x, wk, acc[2 * r]);
                acc[2 * r + 1] = fmaf(f.y, wk, acc[2 * r + 1]);
            }
        }

        // sigmoid via v_rcp_f32 (~1 ulp) instead of the ~10-instr exact divide
        #pragma unroll
        for (int r = 0; r < R; ++r)
            acc[r] = __builtin_amdgcn_rcpf(1.0f + __expf(-acc[r]));

        if (l < LAYERS - 1) {
            __half2 p[R / 2];
            #pragma unroll
            for (int r = 0; r < R / 2; ++r)
                p[r] = __floats2half2_rn(acc[2 * r], acc[2 * r + 1]);
            *(uint4*)&vals[(N_IN + l * H + tid) * R] = *(const uint4*)p;
            __syncthreads();
            // rotate prefetched params in (full unroll -> register renaming)
            #pragma unroll
            for (int k = 0; k < K; ++k) { idxA[k] = idxB[k]; wA[k] = wB[k]; }
            bA = bB;
        } else {
            // final layer: coalesced fp32 stores (lanes -> consecutive h)
            #pragma unroll
            for (int r = 0; r < R; ++r)
                out[(row0 + r) * H + tid] = acc[r];
        }
    }
}

extern "C" void kernel_launch(void* const* d_in, const int* in_sizes, int n_in,
                              void* d_out, int out_size, void* d_ws, size_t ws_size,
                              hipStream_t stream) {
    const float* x        = (const float*)d_in[0];
    const int*   link_idx = (const int*)  d_in[1];
    const float* weights  = (const float*)d_in[2];
    const float* bias     = (const float*)d_in[3];
    float*       out      = (float*)d_out;

    const size_t need = 2 * (size_t)PARAM_N * 4;   // idx2 + w2 = 512 KB

    if (d_ws != nullptr && ws_size >= need) {
        int*   idx2 = (int*)d_ws;
        float* w2   = (float*)((char*)d_ws + PARAM_N * sizeof(int));
        ffn_sched_kernel<<<dim3(64), dim3(64), 0, stream>>>(link_idx, weights, idx2, w2);
        ffn_fused_kernel<1><<<dim3(BATCH / R), dim3(NT), 0, stream>>>(x, idx2, w2, bias, out);
    } else {
        // workspace too small: proven baseline path, no global side-buffers
        ffn_fused_kernel<0><<<dim3(BATCH / R), dim3(NT), 0, stream>>>(x, link_idx, weights, bias, out);
    }
}

// Round 12
// 109.868 us; speedup vs baseline: 2.1806x; 2.1806x over previous
//
#include <hip/hip_runtime.h>
#include <hip/hip_fp16.h>

// L=8 layers, H=512, K=16 links, N_IN=512, B=8192; out = last 512 cols (fp32).
#define LAYERS 8
#define H      512
#define K      16
#define N_IN   512
#define BATCH  8192
#define R      8      // batch rows per block; 8 x f16 = 16 B -> one ds_read_b128 per gather
#define NT     512    // 8 waves/block; 64 KB LDS -> 2 blocks/CU -> 16 waves/CU
// Layer l gathers from cols [0, 512+512*l); max l=7 -> cols < 4096. Layer 7's
// output is never gathered -> straight to global. LDS = 4096*16 B = 64 KB.
#define LDS_COLS 4096

// ============================ SESSION LEDGER =============================
// Best: THIS kernel (R0 structure): dispatch 50-54us, e2e 108.9-109.9us.
// Everything tried against it lost:
//  R5/R7:  static bank-group sort+stagger prep: conflicts only -12% (the
//          16-lane stagger fed each 8-lane HW phase CONSECUTIVE sorted ranks
//          -> concentrated slots); prep dispatch tax ~10us e2e.
//  R8-R10: deeper read queues (rolling dbuf, burst-8+sched_barrier, with and
//          without spill): 55-67us. Compiler's simple schedule wins.
//  R11:    R=4 2x occupancy (72%): 74us. Not TLP-bound.
//  R12:    A/B split 2x ds_read_b64: conflicts 2x, +14us. LAW: counted
//          conflict/instr (~8.2 cyc) is size-independent -> service =
//          width-floor + 8.2; fewest widest reads win.
//  R13/R14: joint wave-level scheduling: prep kernels ran 65/139us (LDS-
//          atomic barriers resp. scratch from runtime-indexed reg arrays,
//          rule #20). Fundamental: per-lane data-dependent permutation of
//          register arrays needs scratch or a memory round-trip; every
//          delivery mechanism costs more than the max ~7us payoff
//          (gather floor = 4096 reads/CU x 12cyc conflict-free b128).
// Roofline case: HBM 7% (irrelevant); LDS gather 27.8us of the ~50us
// dispatch is within ~25% of its measured conflict-free issue floor, the
// rest is VALU (40%) + barriers; e2e carries ~58us fixed harness overhead.
// =========================================================================

__global__ __launch_bounds__(NT, 2)
void ffn_fused_kernel(const float* __restrict__ x,
                      const int*   __restrict__ link_idx,
                      const float* __restrict__ weights,
                      const float* __restrict__ bias,
                      float*       __restrict__ out)
{
    // vals[c*R + r] = f16 value of column c, block batch-row r.
    __shared__ __align__(16) __half vals[LDS_COLS * R];   // 65536 B

    const int tid  = threadIdx.x;
    const int row0 = blockIdx.x * R;

    // ---- Stage x rows into LDS as f16 (each thread owns one column) ----
    {
        const int c = tid;                     // NT == N_IN == 512
        float v[R];
        #pragma unroll
        for (int r = 0; r < R; ++r)
            v[r] = x[(row0 + r) * N_IN + c];   // coalesced per r
        __half2 p[R / 2];
        #pragma unroll
        for (int r = 0; r < R / 2; ++r)
            p[r] = __floats2half2_rn(v[2 * r], v[2 * r + 1]);
        *(uint4*)&vals[c * R] = *(const uint4*)p;   // one ds_write_b128
    }

    // ---- Preload layer-0 params while LDS staging drains (before barrier) ----
    int   idxA[K]; float wA[K]; float bA;
    {
        const int base = tid * K;              // l=0, h=tid
        #pragma unroll
        for (int q = 0; q < 4; ++q) {
            *(int4*)  &idxA[4 * q] = ((const int4*)  (link_idx + base))[q];
            *(float4*)&wA  [4 * q] = ((const float4*)(weights  + base))[q];
        }
        bA = bias[tid];
    }

    __syncthreads();

    // ---- Layers (each thread owns one h; 8 batch rows in registers) ----
    #pragma unroll
    for (int l = 0; l < LAYERS; ++l) {
        // Prefetch next layer's params under this layer's gather/FMA work,
        // instead of stalling on L2 right after the barrier.
        int idxB[K]; float wB[K]; float bB = 0.0f;
        if (l < LAYERS - 1) {
            const int nb = ((l + 1) * H + tid) * K;
            #pragma unroll
            for (int q = 0; q < 4; ++q) {
                *(int4*)  &idxB[4 * q] = ((const int4*)  (link_idx + nb))[q];
                *(float4*)&wB  [4 * q] = ((const float4*)(weights  + nb))[q];
            }
            bB = bias[(l + 1) * H + tid];
        }

        float acc[R];
        #pragma unroll
        for (int r = 0; r < R; ++r) acc[r] = bA;

        #pragma unroll
        for (int k = 0; k < K; ++k) {
            // one ds_read_b128 = 8 rows of column idxA[k]
            const uint4 g = *(const uint4*)&vals[idxA[k] * R];
            const __half2* hp = (const __half2*)&g;
            const float wk = wA[k];
            #pragma unroll
            for (int r = 0; r < R / 2; ++r) {
                const float2 f = __half22float2(hp[r]);   // folds into v_fma_mix_f32
                acc[2 * r]     = fmaf(f.x, wk, acc[2 * r]);
                acc[2 * r + 1] = fmaf(f.y, wk, acc[2 * r + 1]);
            }
        }

        // sigmoid via v_rcp_f32 (~1 ulp) instead of the ~10-instr exact divide
        #pragma unroll
        for (int r = 0; r < R; ++r)
            acc[r] = __builtin_amdgcn_rcpf(1.0f + __expf(-acc[r]));

        if (l < LAYERS - 1) {
            __half2 p[R / 2];
            #pragma unroll
            for (int r = 0; r < R / 2; ++r)
                p[r] = __floats2half2_rn(acc[2 * r], acc[2 * r + 1]);
            *(uint4*)&vals[(N_IN + l * H + tid) * R] = *(const uint4*)p;
            __syncthreads();
            // rotate prefetched params in (full unroll -> register renaming, no moves)
            #pragma unroll
            for (int k = 0; k < K; ++k) { idxA[k] = idxB[k]; wA[k] = wB[k]; }
            bA = bB;
        } else {
            // final layer: coalesced fp32 stores (lanes -> consecutive h)
            #pragma unroll
            for (int r = 0; r < R; ++r)
                out[(row0 + r) * H + tid] = acc[r];
        }
    }
}

extern "C" void kernel_launch(void* const* d_in, const int* in_sizes, int n_in,
                              void* d_out, int out_size, void* d_ws, size_t ws_size,
                              hipStream_t stream) {
    const float* x        = (const float*)d_in[0];
    const int*   link_idx = (const int*)  d_in[1];
    const float* weights  = (const float*)d_in[2];
    const float* bias     = (const float*)d_in[3];
    float*       out      = (float*)d_out;

    ffn_fused_kernel<<<dim3(BATCH / R), dim3(NT), 0, stream>>>(x, link_idx, weights, bias, out);
}